// Round 14
// baseline (441.037 us; speedup 1.0000x reference)
//
#include <hip/hip_runtime.h>
#include <hip/hip_bf16.h>
#include <cstdint>
#include <cstddef>

typedef __hip_bfloat16 bf16;
typedef __attribute__((ext_vector_type(8))) short short8;
typedef __attribute__((ext_vector_type(4))) float f32x4;

#define B_  2
#define T_  2048
#define E_  1024
#define H_  16
#define HS_ 64
#define EPS_ 1e-5f
#define NEG_BIG -1.0e30f
// qk scale (HS^-0.5) x log2(e): scores land in log2 domain
#define SCALE_L2 0.18033688011112042f

__device__ __forceinline__ float b2f(bf16 v) { return __bfloat162float(v); }
__device__ __forceinline__ bf16  f2b(float v) { return __float2bfloat16(v); }
__device__ __forceinline__ ushort f2bs(float v) { bf16 b = __float2bfloat16(v); return *(ushort*)&b; }
__device__ __forceinline__ float ld1(const bf16* p) { return b2f(*p); }
__device__ __forceinline__ float ld1(const float* p) { return *p; }
__device__ __forceinline__ void st1(bf16* p, float v) { *p = f2b(v); }
__device__ __forceinline__ void st1(float* p, float v) { *p = v; }

// async global->LDS, 16B per lane; lds dest = wave-uniform base + lane*16
__device__ __forceinline__ void gload16(const void* g, const void* l) {
    __builtin_amdgcn_global_load_lds(
        (const __attribute__((address_space(1))) unsigned int*)(size_t)g,
        (__attribute__((address_space(3))) unsigned int*)(unsigned int)(size_t)l,
        16, 0, 0);
}

// ---------------------------------------------------------------------------
// 64x64 fp32->bf16 transpose tile (shared buffer passed in)
// ---------------------------------------------------------------------------
__device__ __forceinline__ void transpose_tile_s(short t[64][72],
                                                 const float* in, size_t ldin,
                                                 bf16* out, size_t ldout,
                                                 int r0, int c0)
{
    const int tid = threadIdx.x;
    const int tr = tid >> 2, tc4 = (tid & 3) * 16;

    const float* p = in + (size_t)(r0 + tr) * ldin + c0 + tc4;
    float4 v0 = ((const float4*)p)[0], v1 = ((const float4*)p)[1];
    float4 v2 = ((const float4*)p)[2], v3 = ((const float4*)p)[3];
    union { ushort u[16]; uint4 q[2]; } pk;
    pk.u[0] = f2bs(v0.x); pk.u[1] = f2bs(v0.y); pk.u[2]  = f2bs(v0.z); pk.u[3]  = f2bs(v0.w);
    pk.u[4] = f2bs(v1.x); pk.u[5] = f2bs(v1.y); pk.u[6]  = f2bs(v1.z); pk.u[7]  = f2bs(v1.w);
    pk.u[8] = f2bs(v2.x); pk.u[9] = f2bs(v2.y); pk.u[10] = f2bs(v2.z); pk.u[11] = f2bs(v2.w);
    pk.u[12] = f2bs(v3.x); pk.u[13] = f2bs(v3.y); pk.u[14] = f2bs(v3.z); pk.u[15] = f2bs(v3.w);
    *(uint4*)&t[tr][tc4]     = pk.q[0];
    *(uint4*)&t[tr][tc4 + 8] = pk.q[1];
    __syncthreads();

    const int tcI = tid >> 2, rj = (tid & 3) * 16;
    union { ushort u[16]; uint4 q[2]; } po;
    #pragma unroll
    for (int j = 0; j < 16; j++) po.u[j] = (ushort)t[rj + j][tcI];
    bf16* op = out + (size_t)(c0 + tcI) * ldout + r0 + rj;
    ((uint4*)op)[0] = po.q[0];
    ((uint4*)op)[1] = po.q[1];
}

// ---------------------------------------------------------------------------
// Merged prep A: x->bf16 (2048 blocks) + Wqkv^T (768) + Wo^T (256)
// ---------------------------------------------------------------------------
__global__ __launch_bounds__(256) void prep_kernel(const float* __restrict__ x,
                                                   ushort* __restrict__ xb,
                                                   const float* __restrict__ Wq,
                                                   const float* __restrict__ Wk,
                                                   const float* __restrict__ Wv,
                                                   bf16* __restrict__ WqkvT,
                                                   const float* __restrict__ Wo,
                                                   bf16* __restrict__ WoT)
{
    __shared__ short t[64][72];
    const int bid = blockIdx.x;
    if (bid < 2048) {
        int i = (bid * 256 + (int)threadIdx.x) * 8;
        float4 a = ((const float4*)(x + i))[0];
        float4 b = ((const float4*)(x + i))[1];
        union { ushort u[8]; uint4 v; } p;
        p.u[0] = f2bs(a.x); p.u[1] = f2bs(a.y); p.u[2] = f2bs(a.z); p.u[3] = f2bs(a.w);
        p.u[4] = f2bs(b.x); p.u[5] = f2bs(b.y); p.u[6] = f2bs(b.z); p.u[7] = f2bs(b.w);
        *(uint4*)(xb + i) = p.v;
    } else if (bid < 2048 + 768) {
        const int i = bid - 2048;            // (s 0..47) x (xt 0..15)
        const int s = i >> 4, xt = i & 15;
        const int proj = s >> 4, h = s & 15;
        const float* W = (proj == 0) ? Wq : ((proj == 1) ? Wk : Wv);
        transpose_tile_s(t, W + (size_t)h * E_ * HS_, HS_,
                         WqkvT + ((size_t)proj * E_ + h * 64) * E_, E_,
                         xt * 64, 0);
    } else {
        const int i = bid - 2816;            // 256 tiles of Wo [1024][1024]
        transpose_tile_s(t, Wo, E_, WoT, E_, (i >> 4) * 64, (i & 15) * 64);
    }
}

// ---------------------------------------------------------------------------
// Merged prep B: W1^T (1024 blocks) + W2^T (1024 blocks)
// ---------------------------------------------------------------------------
__global__ __launch_bounds__(256) void prep2_kernel(const float* __restrict__ W1,
                                                    bf16* __restrict__ W1T,
                                                    const float* __restrict__ W2,
                                                    bf16* __restrict__ W2T)
{
    __shared__ short t[64][72];
    const int bid = blockIdx.x;
    if (bid < 1024) {   // W1 [1024][4096] -> W1T [4096][1024]
        transpose_tile_s(t, W1, 4 * E_, W1T, E_,
                         (bid & 15) * 64, (bid >> 4) * 64);
    } else {            // W2 [4096][1024] -> W2T [1024][4096]
        const int i = bid - 1024;
        transpose_tile_s(t, W2, E_, W2T, 4 * E_,
                         (i >> 4) * 64, (i & 15) * 64);
    }
}

// ---------------------------------------------------------------------------
// V transpose (bf16): qkv V-section [T][64] per (b,h) -> vT [b][h][64][T].
// ---------------------------------------------------------------------------
__global__ __launch_bounds__(256) void vt_transpose(const bf16* __restrict__ qkv,
                                                    bf16* __restrict__ vT)
{
    __shared__ short t[64][72];
    const int tid = threadIdx.x;
    const int bh  = blockIdx.y;
    const int b   = bh >> 4, h = bh & 15;
    const int t0  = blockIdx.x * 64;

    const bf16* in = qkv + ((size_t)b * T_) * (3 * E_) + 2 * E_ + h * 64;
    const int tr = tid >> 2, tc4 = (tid & 3) * 16;
    const bf16* p = in + (size_t)(t0 + tr) * (3 * E_) + tc4;
    uint4 q0 = ((const uint4*)p)[0];
    uint4 q1 = ((const uint4*)p)[1];
    *(uint4*)&t[tr][tc4]     = q0;
    *(uint4*)&t[tr][tc4 + 8] = q1;
    __syncthreads();

    const int tcI = tid >> 2, rj = (tid & 3) * 16;
    union { ushort u[16]; uint4 q[2]; } po;
    #pragma unroll
    for (int j = 0; j < 16; j++) po.u[j] = (ushort)t[rj + j][tcI];
    bf16* op = vT + ((size_t)bh * 64 + tcI) * T_ + t0 + rj;
    ((uint4*)op)[0] = po.q[0];
    ((uint4*)op)[1] = po.q[1];
}

// ---------------------------------------------------------------------------
// MFMA GEMM: C[M,N] = A[M,K] @ BT[N,K]^T (+bias fp32)(+relu), bf16 in, TO out.
// Block tile (WROWS*MF*16) x (WCOLS*NF*16), BK = KS*32, 256 thr / 4 waves.
// ---------------------------------------------------------------------------
template <int WROWS, int WCOLS, int MF, int NF, int KS, bool BIAS, bool RELU,
          typename TO>
__global__ __launch_bounds__(256) void gemm_bt(const bf16* __restrict__ A,
                                               const bf16* __restrict__ BT,
                                               const float* __restrict__ bias,
                                               TO* __restrict__ C,
                                               int M, int N, int K)
{
    constexpr int BM = WROWS * MF * 16;
    constexpr int BN = WCOLS * NF * 16;
    __shared__ short Asm[KS][BM][32];
    __shared__ short Bsm[KS][BN][32];

    const int tid  = threadIdx.x;
    const int wv   = tid >> 6, lane = tid & 63;
    const int quad = lane >> 4, l16 = lane & 15;
    const int row0 = blockIdx.y * BM, col0 = blockIdx.x * BN;
    const int mr0  = (wv / WCOLS) * MF * 16;
    const int nc0  = (wv % WCOLS) * NF * 16;

    const int sr = tid >> 2, sc = tid & 3;
    const bf16* Ag = A  + (size_t)(row0 + sr) * K + sc * 8;
    const bf16* Bg = BT + (size_t)(col0 + (sr % BN)) * K + sc * 8;

    f32x4 acc[MF][NF];
    #pragma unroll
    for (int i = 0; i < MF; i++)
        #pragma unroll
        for (int j = 0; j < NF; j++) acc[i][j] = (f32x4){0.f, 0.f, 0.f, 0.f};

    for (int kt = 0; kt < K; kt += 32 * KS) {
        __syncthreads();
        #pragma unroll
        for (int g = 0; g < KS; g++) {
            #pragma unroll
            for (int l = 0; l < BM / 64; l++)
                gload16(Ag + g * 32 + (size_t)l * 64 * K, &Asm[g][l * 64 + wv * 16][0]);
            #pragma unroll
            for (int l = 0; l < BN / 64; l++)
                gload16(Bg + g * 32 + (size_t)l * 64 * K, &Bsm[g][l * 64 + wv * 16][0]);
        }
        Ag += 32 * KS; Bg += 32 * KS;
        __syncthreads();

        #pragma unroll
        for (int g = 0; g < KS; g++) {
            short8 af[MF], bfr[NF];
            #pragma unroll
            for (int mf = 0; mf < MF; mf++)
                af[mf] = *(const short8*)&Asm[g][mr0 + mf * 16 + l16][quad * 8];
            #pragma unroll
            for (int nf = 0; nf < NF; nf++)
                bfr[nf] = *(const short8*)&Bsm[g][nc0 + nf * 16 + l16][quad * 8];
            #pragma unroll
            for (int mf = 0; mf < MF; mf++)
                #pragma unroll
                for (int nf = 0; nf < NF; nf++)
                    acc[mf][nf] = __builtin_amdgcn_mfma_f32_16x16x32_bf16(
                        af[mf], bfr[nf], acc[mf][nf], 0, 0, 0);
        }
    }

    #pragma unroll
    for (int nf = 0; nf < NF; nf++) {
        const int col = col0 + nc0 + nf * 16 + l16;
        const float bv = BIAS ? bias[col] : 0.f;
        #pragma unroll
        for (int mf = 0; mf < MF; mf++) {
            #pragma unroll
            for (int r = 0; r < 4; r++) {
                const int row = row0 + mr0 + mf * 16 + quad * 4 + r;
                float v = acc[mf][nf][r] + bv;
                if (RELU) v = fmaxf(v, 0.f);
                st1(&C[(size_t)row * N + col], v);
            }
        }
    }
}

// ---------------------------------------------------------------------------
// Flash attention (MFMA), work-balanced (paired q-tiles {x, 31-x}), 128-key
// K-stages. exp2-domain softmax (log2e folded into QK scale). Row sums via
// MFMA with a constant all-ones B-frag (replaces 32 adds + shfl butterfly).
// V pre-transposed in vT [bh][64][T]. Masked chunks store exact 0.
// ---------------------------------------------------------------------------
__global__ __launch_bounds__(256) void attn_mfma(const bf16* __restrict__ qkv,
                                                 const bf16* __restrict__ vT,
                                                 bf16* __restrict__ outp)
{
    __shared__ short Klds[128][72];
    __shared__ short Vlds[64][136];
    __shared__ short Plds[4][16][136];

    const int tid  = threadIdx.x;
    const int w    = tid >> 6, lane = tid & 63;
    const int quad = lane >> 4, l16 = lane & 15;
    const int bh   = blockIdx.y;
    const int b    = bh >> 4, h = bh & 15;
    const size_t rowb = (size_t)b * T_ * 3 * E_;

    // constant bf16 1.0 B-frag for row-sum MFMA
    const short one_s = (short)0x3F80;
    const short8 ones8 = {one_s, one_s, one_s, one_s, one_s, one_s, one_s, one_s};

    // K staging map: key = tid>>1 (0..127), d-half = (tid&1)*32
    const int kkey = tid >> 1, kdh = (tid & 1) * 32;
    const bf16* Kg = qkv + rowb + E_ + h * HS_ + kdh;
    // V staging map: d = tid>>2 (0..63), key-seg = (tid&3)*32
    const int vd = tid >> 2, vseg = (tid & 3) * 32;
    const bf16* Vg = vT + ((size_t)bh * 64 + vd) * T_ + vseg;

    for (int pass = 0; pass < 2; pass++) {
        const int t0 = (pass == 0 ? blockIdx.x : 31 - blockIdx.x) * 64;
        const int qbase = t0 + w * 16;

        const bf16* Qp = qkv + rowb + (size_t)(qbase + l16) * (3 * E_) + h * HS_;
        const short8 aq0 = *(const short8*)(Qp + quad * 8);
        const short8 aq1 = *(const short8*)(Qp + 32 + quad * 8);

        f32x4 o[4];
        float mrow[4], lrow[4];
        #pragma unroll
        for (int f = 0; f < 4; f++) o[f] = (f32x4){0.f, 0.f, 0.f, 0.f};
        #pragma unroll
        for (int r = 0; r < 4; r++) { mrow[r] = NEG_BIG; lrow[r] = 0.f; }

        for (int kt0 = 0; kt0 <= t0; kt0 += 128) {
            __syncthreads();   // all reads of prev K/Vlds done
            {
                const int kr = (kt0 + kkey < T_) ? kt0 + kkey : T_ - 1;
                const bf16* kp = Kg + (size_t)kr * (3 * E_);
                *(uint4*)&Klds[kkey][kdh]      = ((const uint4*)kp)[0];
                *(uint4*)&Klds[kkey][kdh + 8]  = ((const uint4*)kp)[1];
                *(uint4*)&Klds[kkey][kdh + 16] = ((const uint4*)kp)[2];
                *(uint4*)&Klds[kkey][kdh + 24] = ((const uint4*)kp)[3];
                const bf16* vp = Vg + kt0;
                *(uint4*)&Vlds[vd][vseg]       = ((const uint4*)vp)[0];
                *(uint4*)&Vlds[vd][vseg + 8]   = ((const uint4*)vp)[1];
                *(uint4*)&Vlds[vd][vseg + 16]  = ((const uint4*)vp)[2];
                *(uint4*)&Vlds[vd][vseg + 24]  = ((const uint4*)vp)[3];
            }
            __syncthreads();   // staging visible

            const bool active = (kt0 <= qbase + 15);       // wave-uniform
            const int nv0 = ((qbase + 15 - kt0) >> 4) + 1; // valid chunks
            const int nvalid = active ? (nv0 < 8 ? nv0 : 8) : 0;

            float p[8][4];
            #pragma unroll
            for (int c = 0; c < 8; c++) {
                if (c < nvalid) {
                    const int kc = kt0 + c * 16;
                    const int krow = c * 16 + l16;
                    short8 bk0 = *(const short8*)&Klds[krow][quad * 8];
                    short8 bk1 = *(const short8*)&Klds[krow][32 + quad * 8];
                    f32x4 s = (f32x4){0.f, 0.f, 0.f, 0.f};
                    s = __builtin_amdgcn_mfma_f32_16x16x32_bf16(aq0, bk0, s, 0, 0, 0);
                    s = __builtin_amdgcn_mfma_f32_16x16x32_bf16(aq1, bk1, s, 0, 0, 0);
                    const int key = kc + l16;
                    #pragma unroll
                    for (int r = 0; r < 4; r++) {
                        float sv = s[r] * SCALE_L2;   // log2 domain
                        if (kc + 15 > qbase && key > qbase + quad * 4 + r)
                            sv = NEG_BIG;
                        p[c][r] = sv;
                    }
                }
            }
            if (active) {
                // running max in log2 domain
                float mx[4];
                #pragma unroll
                for (int r = 0; r < 4; r++) mx[r] = p[0][r];
                #pragma unroll
                for (int c = 1; c < 8; c++)
                    if (c < nvalid)
                        #pragma unroll
                        for (int r = 0; r < 4; r++) mx[r] = fmaxf(mx[r], p[c][r]);
                #pragma unroll
                for (int off = 1; off < 16; off <<= 1)
                    #pragma unroll
                    for (int r = 0; r < 4; r++)
                        mx[r] = fmaxf(mx[r], __shfl_xor(mx[r], off));
                float alpha[4];
                #pragma unroll
                for (int r = 0; r < 4; r++) {
                    const float mnew = fmaxf(mrow[r], mx[r]);
                    alpha[r] = exp2f(mrow[r] - mnew);
                    mrow[r] = mnew;
                    #pragma unroll
                    for (int c = 0; c < 8; c++)
                        p[c][r] = (c < nvalid) ? exp2f(p[c][r] - mnew) : 0.f;
                }
                #pragma unroll
                for (int r = 0; r < 4; r++) {
                    lrow[r] *= alpha[r];
                    #pragma unroll
                    for (int f = 0; f < 4; f++) o[f][r] *= alpha[r];
                }
                #pragma unroll
                for (int c = 0; c < 8; c++)
                    #pragma unroll
                    for (int r = 0; r < 4; r++)
                        Plds[w][quad * 4 + r][c * 16 + l16] = (short)f2bs(p[c][r]);
            }
            // P is wave-private; same-wave LDS ordering by compiler waitcnts
            if (active) {
                f32x4 sacc = (f32x4){0.f, 0.f, 0.f, 0.f};
                #pragma unroll
                for (int kg = 0; kg < 4; kg++) {
                    short8 pa = *(const short8*)&Plds[w][l16][kg * 32 + quad * 8];
                    #pragma unroll
                    for (int f = 0; f < 4; f++) {
                        short8 vb = *(const short8*)&Vlds[f * 16 + l16][kg * 32 + quad * 8];
                        o[f] = __builtin_amdgcn_mfma_f32_16x16x32_bf16(pa, vb, o[f], 0, 0, 0);
                    }
                    sacc = __builtin_amdgcn_mfma_f32_16x16x32_bf16(pa, ones8, sacc, 0, 0, 0);
                }
                #pragma unroll
                for (int r = 0; r < 4; r++) lrow[r] += sacc[r];
            }
        }

        #pragma unroll
        for (int r = 0; r < 4; r++) {
            const float linv = 1.f / lrow[r];
            bf16* op = outp + (size_t)(b * T_ + qbase + quad * 4 + r) * E_ + h * HS_;
            #pragma unroll
            for (int f = 0; f < 4; f++)
                op[f * 16 + l16] = f2b(o[f][r] * linv);
        }
    }
}

// ---------------------------------------------------------------------------
// LayerNorm(a + r)*g + be. One row (E=1024) per block.
// ---------------------------------------------------------------------------
template <typename TA, typename TR, typename TO>
__global__ __launch_bounds__(256) void ln_kernel(const TA* a,
                                                 const TR* r,
                                                 const float* g,
                                                 const float* be,
                                                 TO* out)
{
    const int row = blockIdx.x;
    const TA* pa = a + (size_t)row * E_;
    const TR* pr = r + (size_t)row * E_;
    TO* po = out + (size_t)row * E_;

    float v[4];
    float sum = 0.f, sq = 0.f;
    #pragma unroll
    for (int j = 0; j < 4; j++) {
        int c = threadIdx.x + j * 256;
        v[j] = ld1(pa + c) + ld1(pr + c);
        sum += v[j];
        sq  += v[j] * v[j];
    }
    #pragma unroll
    for (int o = 32; o >= 1; o >>= 1) {
        sum += __shfl_xor(sum, o);
        sq  += __shfl_xor(sq, o);
    }
    __shared__ float red[8];
    const int wave = threadIdx.x >> 6, lane = threadIdx.x & 63;
    if (lane == 0) { red[wave] = sum; red[4 + wave] = sq; }
    __syncthreads();
    sum = red[0] + red[1] + red[2] + red[3];
    sq  = red[4] + red[5] + red[6] + red[7];

    const float mu  = sum * (1.f / E_);
    const float var = fmaxf(sq * (1.f / E_) - mu * mu, 0.f);
    const float rs  = rsqrtf(var + EPS_);

    #pragma unroll
    for (int j = 0; j < 4; j++) {
        int c = threadIdx.x + j * 256;
        st1(po + c, (v[j] - mu) * rs * g[c] + be[c]);
    }
}

// ---------------------------------------------------------------------------
// ws plan (peak 32 MiB; ws_size >= 34 MiB proven). d_out (16 MB fp32) is
// scratch until the end:
//   prepA:  xb @ d_out[0..8M); WqkvT ws[0..6M); WoT ws[30..32M)
//   qkv     ws[6..30M);  vT @ d_out[0..8M);  attnout @ d_out[8..16M)
//   prep2:  W1T ws[0..8M); W2T ws[8..16M)   (qkv/WqkvT dead)
//   proj    ws[16..24M); y ws[24..32M) (WoT dead after Wo-GEMM)
//   FFN:    h -> d_out[0..16M); ff ws[16..24M) (proj dead)
//   LN2: reads y + ff from ws, writes fp32 to d_out. No aliasing.
// ---------------------------------------------------------------------------
extern "C" void kernel_launch(void* const* d_in, const int* in_sizes, int n_in,
                              void* d_out, int out_size, void* d_ws, size_t ws_size,
                              hipStream_t stream)
{
    (void)in_sizes; (void)n_in; (void)out_size; (void)ws_size;
    const float* x   = (const float*)d_in[0];
    const float* Wq  = (const float*)d_in[1];
    const float* Wk  = (const float*)d_in[2];
    const float* Wv  = (const float*)d_in[3];
    const float* Wo  = (const float*)d_in[4];
    const float* bo  = (const float*)d_in[5];
    const float* W1  = (const float*)d_in[6];
    const float* b1  = (const float*)d_in[7];
    const float* W2  = (const float*)d_in[8];
    const float* b2  = (const float*)d_in[9];
    const float* g1  = (const float*)d_in[10];
    const float* be1 = (const float*)d_in[11];
    const float* g2  = (const float*)d_in[12];
    const float* be2 = (const float*)d_in[13];

    const int M = B_ * T_;   // 4096
    char* ws = (char*)d_ws;
    bf16* WqkvT = (bf16*)(ws);                      // 0..6M
    bf16* qkv   = (bf16*)(ws + (size_t)6291456);    // 6..30M
    bf16* WoT   = (bf16*)(ws + (size_t)31457280);   // 30..32M
    bf16* W1T   = (bf16*)(ws);                      // 0..8M   (post-attn)
    bf16* W2T   = (bf16*)(ws + (size_t)8388608);    // 8..16M  (post-attn)
    bf16* proj  = (bf16*)(ws + (size_t)16777216);   // 16..24M
    bf16* y     = (bf16*)(ws + (size_t)25165824);   // 24..32M
    bf16* ff    = (bf16*)(ws + (size_t)16777216);   // 16..24M (proj dead)

    bf16*  xb      = (bf16*)d_out;                            // 0..8M of d_out
    bf16*  vT      = (bf16*)d_out;                            // 0..8M (xb dead)
    bf16*  attnout = (bf16*)((char*)d_out + (size_t)8388608); // 8..16M of d_out
    bf16*  hbuf    = (bf16*)d_out;                            // 0..16M (FFN)
    float* outf    = (float*)d_out;

    // 1) merged prep A: x->bf16, Wqkv^T, Wo^T
    prep_kernel<<<3072, 256, 0, stream>>>(x, (ushort*)xb, Wq, Wk, Wv, WqkvT, Wo, WoT);

    // 2) qkv = xb @ WqkvT^T   [4096,3072], K=1024  (768 blocks, 128x128)
    gemm_bt<2, 2, 4, 4, 1, false, false, bf16><<<dim3(24, 32), 256, 0, stream>>>(
        xb, WqkvT, nullptr, qkv, M, 3 * E_, E_);

    // 3) V^T precompute: qkv V-cols -> vT [bh][64][T]  (xb dead)
    vt_transpose<<<dim3(T_ / 64, B_ * H_), 256, 0, stream>>>(qkv, vT);

    // 4) flash attention -> attnout (paired grid, 512 blocks, 17 stages each)
    attn_mfma<<<dim3(16, B_ * H_), 256, 0, stream>>>(qkv, vT, attnout);

    // 5) merged prep B: W1^T, W2^T (qkv dead)
    prep2_kernel<<<2048, 256, 0, stream>>>(W1, W1T, W2, W2T);

    // 6) proj = attnout @ WoT^T + bo  (128x64 tiles, 512 blocks)
    gemm_bt<2, 2, 4, 2, 1, true, false, bf16><<<dim3(16, 32), 256, 0, stream>>>(
        attnout, WoT, bo, proj, M, E_, E_);

    // 7) y = LN1(x + proj) -> ws[24..32M)
    ln_kernel<float, bf16, bf16><<<M, 256, 0, stream>>>(x, proj, g1, be1, y);

    // 8) FFN in two 2048-row halves; h -> d_out scratch, ff(bf16) -> ws
    for (int half = 0; half < 2; half++) {
        const size_t r0 = (size_t)half * 2048;
        // h = relu(y_half @ W1T^T + b1): 128x128 tiles -> 512 blocks
        gemm_bt<2, 2, 4, 4, 1, true, true, bf16><<<dim3(32, 16), 256, 0, stream>>>(
            y + r0 * E_, W1T, b1, hbuf, 2048, 4 * E_, E_);
        // ff_half = h @ W2T^T + b2: 64x64 tiles, BK=64 -> 512 blocks
        gemm_bt<2, 2, 2, 2, 2, true, false, bf16><<<dim3(16, 32), 256, 0, stream>>>(
            hbuf, W2T, b2, ff + r0 * E_, 2048, E_, 4 * E_);
    }

    // 9) out = LN2(y + ff) -> d_out fp32 (sources in ws, no aliasing)
    ln_kernel<bf16, bf16, float><<<M, 256, 0, stream>>>(y, ff, g2, be2, outf);
}

// Round 15
// 420.562 us; speedup vs baseline: 1.0487x; 1.0487x over previous
//
#include <hip/hip_runtime.h>
#include <hip/hip_bf16.h>
#include <cstdint>
#include <cstddef>

typedef __hip_bfloat16 bf16;
typedef __attribute__((ext_vector_type(8))) short short8;
typedef __attribute__((ext_vector_type(4))) float f32x4;

#define B_  2
#define T_  2048
#define E_  1024
#define H_  16
#define HS_ 64
#define EPS_ 1e-5f
#define NEG_BIG -1.0e30f

__device__ __forceinline__ float b2f(bf16 v) { return __bfloat162float(v); }
__device__ __forceinline__ bf16  f2b(float v) { return __float2bfloat16(v); }
__device__ __forceinline__ ushort f2bs(float v) { bf16 b = __float2bfloat16(v); return *(ushort*)&b; }
__device__ __forceinline__ float ld1(const bf16* p) { return b2f(*p); }
__device__ __forceinline__ float ld1(const float* p) { return *p; }
__device__ __forceinline__ void st1(bf16* p, float v) { *p = f2b(v); }
__device__ __forceinline__ void st1(float* p, float v) { *p = v; }

// async global->LDS, 16B per lane; lds dest = wave-uniform base + lane*16
__device__ __forceinline__ void gload16(const void* g, const void* l) {
    __builtin_amdgcn_global_load_lds(
        (const __attribute__((address_space(1))) unsigned int*)(size_t)g,
        (__attribute__((address_space(3))) unsigned int*)(unsigned int)(size_t)l,
        16, 0, 0);
}

// ---------------------------------------------------------------------------
// 64x64 fp32->bf16 transpose tile (shared buffer passed in)
// ---------------------------------------------------------------------------
__device__ __forceinline__ void transpose_tile_s(short t[64][72],
                                                 const float* in, size_t ldin,
                                                 bf16* out, size_t ldout,
                                                 int r0, int c0)
{
    const int tid = threadIdx.x;
    const int tr = tid >> 2, tc4 = (tid & 3) * 16;

    const float* p = in + (size_t)(r0 + tr) * ldin + c0 + tc4;
    float4 v0 = ((const float4*)p)[0], v1 = ((const float4*)p)[1];
    float4 v2 = ((const float4*)p)[2], v3 = ((const float4*)p)[3];
    union { ushort u[16]; uint4 q[2]; } pk;
    pk.u[0] = f2bs(v0.x); pk.u[1] = f2bs(v0.y); pk.u[2]  = f2bs(v0.z); pk.u[3]  = f2bs(v0.w);
    pk.u[4] = f2bs(v1.x); pk.u[5] = f2bs(v1.y); pk.u[6]  = f2bs(v1.z); pk.u[7]  = f2bs(v1.w);
    pk.u[8] = f2bs(v2.x); pk.u[9] = f2bs(v2.y); pk.u[10] = f2bs(v2.z); pk.u[11] = f2bs(v2.w);
    pk.u[12] = f2bs(v3.x); pk.u[13] = f2bs(v3.y); pk.u[14] = f2bs(v3.z); pk.u[15] = f2bs(v3.w);
    *(uint4*)&t[tr][tc4]     = pk.q[0];
    *(uint4*)&t[tr][tc4 + 8] = pk.q[1];
    __syncthreads();

    const int tcI = tid >> 2, rj = (tid & 3) * 16;
    union { ushort u[16]; uint4 q[2]; } po;
    #pragma unroll
    for (int j = 0; j < 16; j++) po.u[j] = (ushort)t[rj + j][tcI];
    bf16* op = out + (size_t)(c0 + tcI) * ldout + r0 + rj;
    ((uint4*)op)[0] = po.q[0];
    ((uint4*)op)[1] = po.q[1];
}

// ---------------------------------------------------------------------------
// Merged prep A: x->bf16 (2048 blocks) + Wqkv^T (768) + Wo^T (256)
// ---------------------------------------------------------------------------
__global__ __launch_bounds__(256) void prep_kernel(const float* __restrict__ x,
                                                   ushort* __restrict__ xb,
                                                   const float* __restrict__ Wq,
                                                   const float* __restrict__ Wk,
                                                   const float* __restrict__ Wv,
                                                   bf16* __restrict__ WqkvT,
                                                   const float* __restrict__ Wo,
                                                   bf16* __restrict__ WoT)
{
    __shared__ short t[64][72];
    const int bid = blockIdx.x;
    if (bid < 2048) {
        int i = (bid * 256 + (int)threadIdx.x) * 8;
        float4 a = ((const float4*)(x + i))[0];
        float4 b = ((const float4*)(x + i))[1];
        union { ushort u[8]; uint4 v; } p;
        p.u[0] = f2bs(a.x); p.u[1] = f2bs(a.y); p.u[2] = f2bs(a.z); p.u[3] = f2bs(a.w);
        p.u[4] = f2bs(b.x); p.u[5] = f2bs(b.y); p.u[6] = f2bs(b.z); p.u[7] = f2bs(b.w);
        *(uint4*)(xb + i) = p.v;
    } else if (bid < 2048 + 768) {
        const int i = bid - 2048;            // (s 0..47) x (xt 0..15)
        const int s = i >> 4, xt = i & 15;
        const int proj = s >> 4, h = s & 15;
        const float* W = (proj == 0) ? Wq : ((proj == 1) ? Wk : Wv);
        transpose_tile_s(t, W + (size_t)h * E_ * HS_, HS_,
                         WqkvT + ((size_t)proj * E_ + h * 64) * E_, E_,
                         xt * 64, 0);
    } else {
        const int i = bid - 2816;            // 256 tiles of Wo [1024][1024]
        transpose_tile_s(t, Wo, E_, WoT, E_, (i >> 4) * 64, (i & 15) * 64);
    }
}

// ---------------------------------------------------------------------------
// Merged prep B: W1^T (1024 blocks) + W2^T (1024 blocks)
// ---------------------------------------------------------------------------
__global__ __launch_bounds__(256) void prep2_kernel(const float* __restrict__ W1,
                                                    bf16* __restrict__ W1T,
                                                    const float* __restrict__ W2,
                                                    bf16* __restrict__ W2T)
{
    __shared__ short t[64][72];
    const int bid = blockIdx.x;
    if (bid < 1024) {   // W1 [1024][4096] -> W1T [4096][1024]
        transpose_tile_s(t, W1, 4 * E_, W1T, E_,
                         (bid & 15) * 64, (bid >> 4) * 64);
    } else {            // W2 [4096][1024] -> W2T [1024][4096]
        const int i = bid - 1024;
        transpose_tile_s(t, W2, E_, W2T, 4 * E_,
                         (i >> 4) * 64, (i & 15) * 64);
    }
}

// ---------------------------------------------------------------------------
// V transpose (bf16): qkv V-section [T][64] per (b,h) -> vT [b][h][64][T].
// ---------------------------------------------------------------------------
__global__ __launch_bounds__(256) void vt_transpose(const bf16* __restrict__ qkv,
                                                    bf16* __restrict__ vT)
{
    __shared__ short t[64][72];
    const int tid = threadIdx.x;
    const int bh  = blockIdx.y;
    const int b   = bh >> 4, h = bh & 15;
    const int t0  = blockIdx.x * 64;

    const bf16* in = qkv + ((size_t)b * T_) * (3 * E_) + 2 * E_ + h * 64;
    const int tr = tid >> 2, tc4 = (tid & 3) * 16;
    const bf16* p = in + (size_t)(t0 + tr) * (3 * E_) + tc4;
    uint4 q0 = ((const uint4*)p)[0];
    uint4 q1 = ((const uint4*)p)[1];
    *(uint4*)&t[tr][tc4]     = q0;
    *(uint4*)&t[tr][tc4 + 8] = q1;
    __syncthreads();

    const int tcI = tid >> 2, rj = (tid & 3) * 16;
    union { ushort u[16]; uint4 q[2]; } po;
    #pragma unroll
    for (int j = 0; j < 16; j++) po.u[j] = (ushort)t[rj + j][tcI];
    bf16* op = vT + ((size_t)bh * 64 + tcI) * T_ + t0 + rj;
    ((uint4*)op)[0] = po.q[0];
    ((uint4*)op)[1] = po.q[1];
}

// ---------------------------------------------------------------------------
// MFMA GEMM: C[M,N] = A[M,K] @ BT[N,K]^T (+bias fp32)(+relu), bf16 in, TO out.
// Block tile (WROWS*MF*16) x (WCOLS*NF*16), BK = KS*32, 256 thr / 4 waves.
// KS separate unpadded 32-wide LDS banks keep gload16 contiguity AND the
// 2-way-free bank stride.
// ---------------------------------------------------------------------------
template <int WROWS, int WCOLS, int MF, int NF, int KS, bool BIAS, bool RELU,
          typename TO>
__global__ __launch_bounds__(256) void gemm_bt(const bf16* __restrict__ A,
                                               const bf16* __restrict__ BT,
                                               const float* __restrict__ bias,
                                               TO* __restrict__ C,
                                               int M, int N, int K)
{
    constexpr int BM = WROWS * MF * 16;
    constexpr int BN = WCOLS * NF * 16;
    __shared__ short Asm[KS][BM][32];
    __shared__ short Bsm[KS][BN][32];

    const int tid  = threadIdx.x;
    const int wv   = tid >> 6, lane = tid & 63;
    const int quad = lane >> 4, l16 = lane & 15;
    const int row0 = blockIdx.y * BM, col0 = blockIdx.x * BN;
    const int mr0  = (wv / WCOLS) * MF * 16;
    const int nc0  = (wv % WCOLS) * NF * 16;

    const int sr = tid >> 2, sc = tid & 3;
    const bf16* Ag = A  + (size_t)(row0 + sr) * K + sc * 8;
    const bf16* Bg = BT + (size_t)(col0 + (sr % BN)) * K + sc * 8;

    f32x4 acc[MF][NF];
    #pragma unroll
    for (int i = 0; i < MF; i++)
        #pragma unroll
        for (int j = 0; j < NF; j++) acc[i][j] = (f32x4){0.f, 0.f, 0.f, 0.f};

    for (int kt = 0; kt < K; kt += 32 * KS) {
        __syncthreads();
        #pragma unroll
        for (int g = 0; g < KS; g++) {
            #pragma unroll
            for (int l = 0; l < BM / 64; l++)
                gload16(Ag + g * 32 + (size_t)l * 64 * K, &Asm[g][l * 64 + wv * 16][0]);
            #pragma unroll
            for (int l = 0; l < BN / 64; l++)
                gload16(Bg + g * 32 + (size_t)l * 64 * K, &Bsm[g][l * 64 + wv * 16][0]);
        }
        Ag += 32 * KS; Bg += 32 * KS;
        __syncthreads();

        #pragma unroll
        for (int g = 0; g < KS; g++) {
            short8 af[MF], bfr[NF];
            #pragma unroll
            for (int mf = 0; mf < MF; mf++)
                af[mf] = *(const short8*)&Asm[g][mr0 + mf * 16 + l16][quad * 8];
            #pragma unroll
            for (int nf = 0; nf < NF; nf++)
                bfr[nf] = *(const short8*)&Bsm[g][nc0 + nf * 16 + l16][quad * 8];
            #pragma unroll
            for (int mf = 0; mf < MF; mf++)
                #pragma unroll
                for (int nf = 0; nf < NF; nf++)
                    acc[mf][nf] = __builtin_amdgcn_mfma_f32_16x16x32_bf16(
                        af[mf], bfr[nf], acc[mf][nf], 0, 0, 0);
        }
    }

    #pragma unroll
    for (int nf = 0; nf < NF; nf++) {
        const int col = col0 + nc0 + nf * 16 + l16;
        const float bv = BIAS ? bias[col] : 0.f;
        #pragma unroll
        for (int mf = 0; mf < MF; mf++) {
            #pragma unroll
            for (int r = 0; r < 4; r++) {
                const int row = row0 + mr0 + mf * 16 + quad * 4 + r;
                float v = acc[mf][nf][r] + bv;
                if (RELU) v = fmaxf(v, 0.f);
                st1(&C[(size_t)row * N + col], v);
            }
        }
    }
}

// ---------------------------------------------------------------------------
// Flash attention (MFMA) — round-13 exact structure (measured 82.5 us):
// paired q-tiles {x, 31-x}, 128-key stages, __expf softmax, shfl-butterfly
// row sums. V pre-transposed in vT [bh][64][T]. Masked chunks store 0.
// ---------------------------------------------------------------------------
__global__ __launch_bounds__(256) void attn_mfma(const bf16* __restrict__ qkv,
                                                 const bf16* __restrict__ vT,
                                                 bf16* __restrict__ outp)
{
    __shared__ short Klds[128][72];
    __shared__ short Vlds[64][136];
    __shared__ short Plds[4][16][136];

    const int tid  = threadIdx.x;
    const int w    = tid >> 6, lane = tid & 63;
    const int quad = lane >> 4, l16 = lane & 15;
    const int bh   = blockIdx.y;
    const int b    = bh >> 4, h = bh & 15;
    const size_t rowb = (size_t)b * T_ * 3 * E_;

    // K staging map: key = tid>>1 (0..127), d-half = (tid&1)*32
    const int kkey = tid >> 1, kdh = (tid & 1) * 32;
    const bf16* Kg = qkv + rowb + E_ + h * HS_ + kdh;
    // V staging map: d = tid>>2 (0..63), key-seg = (tid&3)*32
    const int vd = tid >> 2, vseg = (tid & 3) * 32;
    const bf16* Vg = vT + ((size_t)bh * 64 + vd) * T_ + vseg;

    for (int pass = 0; pass < 2; pass++) {
        const int t0 = (pass == 0 ? blockIdx.x : 31 - blockIdx.x) * 64;
        const int qbase = t0 + w * 16;

        const bf16* Qp = qkv + rowb + (size_t)(qbase + l16) * (3 * E_) + h * HS_;
        const short8 aq0 = *(const short8*)(Qp + quad * 8);
        const short8 aq1 = *(const short8*)(Qp + 32 + quad * 8);

        f32x4 o[4];
        float mrow[4], lrow[4];
        #pragma unroll
        for (int f = 0; f < 4; f++) o[f] = (f32x4){0.f, 0.f, 0.f, 0.f};
        #pragma unroll
        for (int r = 0; r < 4; r++) { mrow[r] = NEG_BIG; lrow[r] = 0.f; }

        for (int kt0 = 0; kt0 <= t0; kt0 += 128) {
            __syncthreads();   // all reads of prev K/Vlds done
            {
                const int kr = (kt0 + kkey < T_) ? kt0 + kkey : T_ - 1;
                const bf16* kp = Kg + (size_t)kr * (3 * E_);
                *(uint4*)&Klds[kkey][kdh]      = ((const uint4*)kp)[0];
                *(uint4*)&Klds[kkey][kdh + 8]  = ((const uint4*)kp)[1];
                *(uint4*)&Klds[kkey][kdh + 16] = ((const uint4*)kp)[2];
                *(uint4*)&Klds[kkey][kdh + 24] = ((const uint4*)kp)[3];
                const bf16* vp = Vg + kt0;
                *(uint4*)&Vlds[vd][vseg]       = ((const uint4*)vp)[0];
                *(uint4*)&Vlds[vd][vseg + 8]   = ((const uint4*)vp)[1];
                *(uint4*)&Vlds[vd][vseg + 16]  = ((const uint4*)vp)[2];
                *(uint4*)&Vlds[vd][vseg + 24]  = ((const uint4*)vp)[3];
            }
            __syncthreads();   // staging visible

            const bool active = (kt0 <= qbase + 15);       // wave-uniform
            const int nv0 = ((qbase + 15 - kt0) >> 4) + 1; // valid chunks
            const int nvalid = active ? (nv0 < 8 ? nv0 : 8) : 0;

            float p[8][4];
            #pragma unroll
            for (int c = 0; c < 8; c++) {
                if (c < nvalid) {
                    const int kc = kt0 + c * 16;
                    const int krow = c * 16 + l16;
                    short8 bk0 = *(const short8*)&Klds[krow][quad * 8];
                    short8 bk1 = *(const short8*)&Klds[krow][32 + quad * 8];
                    f32x4 s = (f32x4){0.f, 0.f, 0.f, 0.f};
                    s = __builtin_amdgcn_mfma_f32_16x16x32_bf16(aq0, bk0, s, 0, 0, 0);
                    s = __builtin_amdgcn_mfma_f32_16x16x32_bf16(aq1, bk1, s, 0, 0, 0);
                    const int key = kc + l16;
                    #pragma unroll
                    for (int r = 0; r < 4; r++) {
                        float sv = s[r] * 0.125f;
                        if (kc + 15 > qbase && key > qbase + quad * 4 + r)
                            sv = NEG_BIG;
                        p[c][r] = sv;
                    }
                }
            }
            if (active) {
                // one softmax update per 128 keys
                float mx[4];
                #pragma unroll
                for (int r = 0; r < 4; r++) mx[r] = p[0][r];
                #pragma unroll
                for (int c = 1; c < 8; c++)
                    if (c < nvalid)
                        #pragma unroll
                        for (int r = 0; r < 4; r++) mx[r] = fmaxf(mx[r], p[c][r]);
                #pragma unroll
                for (int off = 1; off < 16; off <<= 1)
                    #pragma unroll
                    for (int r = 0; r < 4; r++)
                        mx[r] = fmaxf(mx[r], __shfl_xor(mx[r], off));
                float alpha[4], rs[4];
                #pragma unroll
                for (int r = 0; r < 4; r++) {
                    const float mnew = fmaxf(mrow[r], mx[r]);
                    alpha[r] = __expf(mrow[r] - mnew);
                    mrow[r] = mnew;
                    rs[r] = 0.f;
                    #pragma unroll
                    for (int c = 0; c < 8; c++) {
                        p[c][r] = (c < nvalid) ? __expf(p[c][r] - mnew) : 0.f;
                        rs[r] += p[c][r];
                    }
                }
                #pragma unroll
                for (int off = 1; off < 16; off <<= 1)
                    #pragma unroll
                    for (int r = 0; r < 4; r++)
                        rs[r] += __shfl_xor(rs[r], off);
                #pragma unroll
                for (int r = 0; r < 4; r++) {
                    lrow[r] = lrow[r] * alpha[r] + rs[r];
                    #pragma unroll
                    for (int f = 0; f < 4; f++) o[f][r] *= alpha[r];
                }
                #pragma unroll
                for (int c = 0; c < 8; c++)
                    #pragma unroll
                    for (int r = 0; r < 4; r++)
                        Plds[w][quad * 4 + r][c * 16 + l16] = (short)f2bs(p[c][r]);
            }
            // P is wave-private; same-wave LDS ordering by compiler waitcnts
            if (active) {
                #pragma unroll
                for (int kg = 0; kg < 4; kg++) {
                    short8 pa = *(const short8*)&Plds[w][l16][kg * 32 + quad * 8];
                    #pragma unroll
                    for (int f = 0; f < 4; f++) {
                        short8 vb = *(const short8*)&Vlds[f * 16 + l16][kg * 32 + quad * 8];
                        o[f] = __builtin_amdgcn_mfma_f32_16x16x32_bf16(pa, vb, o[f], 0, 0, 0);
                    }
                }
            }
        }

        #pragma unroll
        for (int r = 0; r < 4; r++) {
            const float linv = 1.f / lrow[r];
            bf16* op = outp + (size_t)(b * T_ + qbase + quad * 4 + r) * E_ + h * HS_;
            #pragma unroll
            for (int f = 0; f < 4; f++)
                op[f * 16 + l16] = f2b(o[f][r] * linv);
        }
    }
}

// ---------------------------------------------------------------------------
// LayerNorm(a + r)*g + be. One row (E=1024) per block.
// ---------------------------------------------------------------------------
template <typename TA, typename TR, typename TO>
__global__ __launch_bounds__(256) void ln_kernel(const TA* a,
                                                 const TR* r,
                                                 const float* g,
                                                 const float* be,
                                                 TO* out)
{
    const int row = blockIdx.x;
    const TA* pa = a + (size_t)row * E_;
    const TR* pr = r + (size_t)row * E_;
    TO* po = out + (size_t)row * E_;

    float v[4];
    float sum = 0.f, sq = 0.f;
    #pragma unroll
    for (int j = 0; j < 4; j++) {
        int c = threadIdx.x + j * 256;
        v[j] = ld1(pa + c) + ld1(pr + c);
        sum += v[j];
        sq  += v[j] * v[j];
    }
    #pragma unroll
    for (int o = 32; o >= 1; o >>= 1) {
        sum += __shfl_xor(sum, o);
        sq  += __shfl_xor(sq, o);
    }
    __shared__ float red[8];
    const int wave = threadIdx.x >> 6, lane = threadIdx.x & 63;
    if (lane == 0) { red[wave] = sum; red[4 + wave] = sq; }
    __syncthreads();
    sum = red[0] + red[1] + red[2] + red[3];
    sq  = red[4] + red[5] + red[6] + red[7];

    const float mu  = sum * (1.f / E_);
    const float var = fmaxf(sq * (1.f / E_) - mu * mu, 0.f);
    const float rs  = rsqrtf(var + EPS_);

    #pragma unroll
    for (int j = 0; j < 4; j++) {
        int c = threadIdx.x + j * 256;
        st1(po + c, (v[j] - mu) * rs * g[c] + be[c]);
    }
}

// ---------------------------------------------------------------------------
// ws plan (peak 32 MiB; ws_size >= 34 MiB proven). d_out (16 MB fp32) is
// scratch until the end:
//   prepA:  xb @ d_out[0..8M); WqkvT ws[0..6M); WoT ws[30..32M)
//   qkv     ws[6..30M);  vT @ d_out[0..8M);  attnout @ d_out[8..16M)
//   prep2:  W1T ws[0..8M); W2T ws[8..16M)   (qkv/WqkvT dead)
//   proj    ws[16..24M); y ws[24..32M) (WoT dead after Wo-GEMM)
//   FFN:    h -> d_out[0..16M); ff ws[16..24M) (proj dead)
//   LN2: reads y + ff from ws, writes fp32 to d_out. No aliasing.
// ---------------------------------------------------------------------------
extern "C" void kernel_launch(void* const* d_in, const int* in_sizes, int n_in,
                              void* d_out, int out_size, void* d_ws, size_t ws_size,
                              hipStream_t stream)
{
    (void)in_sizes; (void)n_in; (void)out_size; (void)ws_size;
    const float* x   = (const float*)d_in[0];
    const float* Wq  = (const float*)d_in[1];
    const float* Wk  = (const float*)d_in[2];
    const float* Wv  = (const float*)d_in[3];
    const float* Wo  = (const float*)d_in[4];
    const float* bo  = (const float*)d_in[5];
    const float* W1  = (const float*)d_in[6];
    const float* b1  = (const float*)d_in[7];
    const float* W2  = (const float*)d_in[8];
    const float* b2  = (const float*)d_in[9];
    const float* g1  = (const float*)d_in[10];
    const float* be1 = (const float*)d_in[11];
    const float* g2  = (const float*)d_in[12];
    const float* be2 = (const float*)d_in[13];

    const int M = B_ * T_;   // 4096
    char* ws = (char*)d_ws;
    bf16* WqkvT = (bf16*)(ws);                      // 0..6M
    bf16* qkv   = (bf16*)(ws + (size_t)6291456);    // 6..30M
    bf16* WoT   = (bf16*)(ws + (size_t)31457280);   // 30..32M
    bf16* W1T   = (bf16*)(ws);                      // 0..8M   (post-attn)
    bf16* W2T   = (bf16*)(ws + (size_t)8388608);    // 8..16M  (post-attn)
    bf16* proj  = (bf16*)(ws + (size_t)16777216);   // 16..24M
    bf16* y     = (bf16*)(ws + (size_t)25165824);   // 24..32M
    bf16* ff    = (bf16*)(ws + (size_t)16777216);   // 16..24M (proj dead)

    bf16*  xb      = (bf16*)d_out;                            // 0..8M of d_out
    bf16*  vT      = (bf16*)d_out;                            // 0..8M (xb dead)
    bf16*  attnout = (bf16*)((char*)d_out + (size_t)8388608); // 8..16M of d_out
    bf16*  hbuf    = (bf16*)d_out;                            // 0..16M (FFN)
    float* outf    = (float*)d_out;

    // 1) merged prep A: x->bf16, Wqkv^T, Wo^T
    prep_kernel<<<3072, 256, 0, stream>>>(x, (ushort*)xb, Wq, Wk, Wv, WqkvT, Wo, WoT);

    // 2) qkv = xb @ WqkvT^T  [4096,3072], K=1024  (768 blocks, 128x128, BK=64)
    gemm_bt<2, 2, 4, 4, 2, false, false, bf16><<<dim3(24, 32), 256, 0, stream>>>(
        xb, WqkvT, nullptr, qkv, M, 3 * E_, E_);

    // 3) V^T precompute: qkv V-cols -> vT [bh][64][T]  (xb dead)
    vt_transpose<<<dim3(T_ / 64, B_ * H_), 256, 0, stream>>>(qkv, vT);

    // 4) flash attention -> attnout (paired grid, 512 blocks, 17 stages each)
    attn_mfma<<<dim3(16, B_ * H_), 256, 0, stream>>>(qkv, vT, attnout);

    // 5) merged prep B: W1^T, W2^T (qkv dead)
    prep2_kernel<<<2048, 256, 0, stream>>>(W1, W1T, W2, W2T);

    // 6) proj = attnout @ WoT^T + bo  (128x64 tiles, BK=64, 512 blocks)
    gemm_bt<2, 2, 4, 2, 2, true, false, bf16><<<dim3(16, 32), 256, 0, stream>>>(
        attnout, WoT, bo, proj, M, E_, E_);

    // 7) y = LN1(x + proj) -> ws[24..32M)
    ln_kernel<float, bf16, bf16><<<M, 256, 0, stream>>>(x, proj, g1, be1, y);

    // 8) FFN in two 2048-row halves; h -> d_out scratch, ff(bf16) -> ws
    for (int half = 0; half < 2; half++) {
        const size_t r0 = (size_t)half * 2048;
        // h = relu(y_half @ W1T^T + b1): 128x128, BK=64 -> 512 blocks
        gemm_bt<2, 2, 4, 4, 2, true, true, bf16><<<dim3(32, 16), 256, 0, stream>>>(
            y + r0 * E_, W1T, b1, hbuf, 2048, 4 * E_, E_);
        // ff_half = h @ W2T^T + b2: 64x64 tiles, BK=64 -> 512 blocks
        gemm_bt<2, 2, 2, 2, 2, true, false, bf16><<<dim3(16, 32), 256, 0, stream>>>(
            hbuf, W2T, b2, ff + r0 * E_, 2048, E_, 4 * E_);
    }

    // 9) out = LN2(y + ff) -> d_out fp32 (sources in ws, no aliasing)
    ln_kernel<bf16, bf16, float><<<M, 256, 0, stream>>>(y, ff, g2, be2, outf);
}